// Round 4
// baseline (834.481 us; speedup 1.0000x reference)
//
#include <hip/hip_runtime.h>
#include <math.h>

#define NN 50000
#define NE 800000
#define BETAF 0.1f
#define INVB 10.0f
#define BW 6250      // bucket width: NN/8
#define BPB 512      // blocks per bucket in k_edge4

typedef _Float16 half8v __attribute__((ext_vector_type(8)));
typedef _Float16 half2v __attribute__((ext_vector_type(2)));
typedef float floatx4 __attribute__((ext_vector_type(4)));

// ---------- helpers ----------
__device__ __forceinline__ float sc_(float s, float m, float mn){
  return (s == 0.f) ? 0.f : s * expf(m - mn);
}
__device__ __forceinline__ void red16(float& v){
  v += __shfl_xor(v, 1, 64); v += __shfl_xor(v, 2, 64);
  v += __shfl_xor(v, 4, 64); v += __shfl_xor(v, 8, 64);
}
__device__ __forceinline__ void lse16(float& m, float& s){
  #pragma unroll
  for (int off = 1; off < 16; off <<= 1){
    float mo = __shfl_xor(m, off, 64), so = __shfl_xor(s, off, 64);
    float mn = fmaxf(m, mo);
    s = sc_(s, m, mn) + sc_(so, mo, mn); m = mn;
  }
}
__device__ __forceinline__ float dot2acc(half2v a, half2v b, float c){
#if __has_builtin(__builtin_amdgcn_fdot2)
  return __builtin_amdgcn_fdot2(a, b, c, false);
#else
  return c + (float)a[0]*(float)b[0] + (float)a[1]*(float)b[1];
#endif
}

// ---------- degree histogram ----------
__launch_bounds__(256)
__global__ void k_hist(const int* __restrict__ ei, int* __restrict__ cs, int* __restrict__ cd){
  int e = blockIdx.x*256 + threadIdx.x;
  if (e >= NE) return;
  atomicAdd(&cs[ei[e]], 1);
  atomicAdd(&cd[ei[NE + e]], 1);
}

// ---------- 3-phase exclusive scan ----------
__launch_bounds__(256)
__global__ void k_scan_a(const int* __restrict__ inA, const int* __restrict__ inB,
                         int* __restrict__ outA, int* __restrict__ outB,
                         int* __restrict__ partA, int* __restrict__ partB, int n){
  const int* in = blockIdx.y ? inB : inA;
  int* out = blockIdx.y ? outB : outA;
  int* part = blockIdx.y ? partB : partA;
  int i = blockIdx.x*256 + threadIdx.x;
  int v = (i < n) ? in[i] : 0;
  int lane = threadIdx.x & 63, wid = threadIdx.x >> 6;
  int x = v;
  #pragma unroll
  for (int off = 1; off < 64; off <<= 1){
    int t = __shfl_up(x, off, 64);
    if (lane >= off) x += t;
  }
  __shared__ int wsum[4];
  if (lane == 63) wsum[wid] = x;
  __syncthreads();
  int base = 0;
  #pragma unroll
  for (int w = 0; w < 4; ++w) if (w < wid) base += wsum[w];
  if (i < n) out[i] = base + x - v;
  if (threadIdx.x == 255) part[blockIdx.x] = base + x;
}

__launch_bounds__(256)
__global__ void k_scan_b(int* __restrict__ partA, int* __restrict__ partB, int np){
  int* part = blockIdx.y ? partB : partA;
  int i = threadIdx.x;
  int v = (i < np) ? part[i] : 0;
  int lane = threadIdx.x & 63, wid = threadIdx.x >> 6;
  int x = v;
  #pragma unroll
  for (int off = 1; off < 64; off <<= 1){
    int t = __shfl_up(x, off, 64);
    if (lane >= off) x += t;
  }
  __shared__ int wsum[4];
  if (lane == 63) wsum[wid] = x;
  __syncthreads();
  int base = 0;
  #pragma unroll
  for (int w = 0; w < 4; ++w) if (w < wid) base += wsum[w];
  if (i < np) part[i] = base + x - v;
}

__launch_bounds__(256)
__global__ void k_scan_c(int* __restrict__ outA, int* __restrict__ outB,
                         int* __restrict__ curA, int* __restrict__ curB,
                         const int* __restrict__ partA, const int* __restrict__ partB, int n){
  int* out = blockIdx.y ? outB : outA;
  int* cur = blockIdx.y ? curB : curA;
  const int* part = blockIdx.y ? partB : partA;
  int i = blockIdx.x*256 + threadIdx.x;
  if (i < n){
    int f = out[i] + part[blockIdx.x];
    out[i] = f;
    cur[i] = f;
  }
  if (blockIdx.x == 0 && threadIdx.x == 0) out[n] = NE;
}

// ---------- CSR scatter ----------
__launch_bounds__(256)
__global__ void k_scatter(const int* __restrict__ ei, int* __restrict__ cur_s, int* __restrict__ cur_d,
                          int* __restrict__ src_of_j, int* __restrict__ dst_csr,
                          int* __restrict__ src_dord, int* __restrict__ rs_dord){
  int e = blockIdx.x*256 + threadIdx.x;
  if (e >= NE) return;
  int s = ei[e], d = ei[NE + e];
  int js = atomicAdd(&cur_s[s], 1);
  src_of_j[js] = s;
  dst_csr[js] = d;
  int jd = atomicAdd(&cur_d[d], 1);
  src_dord[jd] = s;
  rs_dord[jd] = js;
}

// ---------- clamped uint8 degrees ----------
__launch_bounds__(256)
__global__ void k_deg(const int* __restrict__ row_s, const int* __restrict__ row_d,
                      unsigned char* __restrict__ d8o, unsigned char* __restrict__ d8i){
  int n = blockIdx.x*256 + threadIdx.x;
  if (n >= NN) return;
  int a = row_s[n+1] - row_s[n];
  int b = row_d[n+1] - row_d[n];
  d8o[n] = (unsigned char)(a > 127 ? 127 : a);
  d8i[n] = (unsigned char)(b > 127 ? 127 : b);
}

// ---------- dst-bucket histogram (XCD slicing) ----------
__launch_bounds__(256)
__global__ void k_bhist(const int* __restrict__ dst_csr, int* __restrict__ bcnt){
  __shared__ int h[8];
  if (threadIdx.x < 8) h[threadIdx.x] = 0;
  __syncthreads();
  int j = blockIdx.x*256 + threadIdx.x;
  if (j < NE) atomicAdd(&h[dst_csr[j]/BW], 1);
  __syncthreads();
  if (threadIdx.x < 8) atomicAdd(&bcnt[threadIdx.x], h[threadIdx.x]);
}

__launch_bounds__(64)
__global__ void k_bscan(const int* __restrict__ bcnt, int* __restrict__ boff, int* __restrict__ bcur){
  if (threadIdx.x == 0){
    int acc = 0;
    for (int i = 0; i < 8; ++i){ boff[i] = acc; bcur[i] = acc; acc += bcnt[i]; }
    boff[8] = acc;
  }
}

// ---------- bucket scatter (block-granular stable: keeps src locality) ----------
__launch_bounds__(256)
__global__ void k_bscatter(const int* __restrict__ src_of_j, const int* __restrict__ dst_csr,
                           int* __restrict__ bcur,
                           int* __restrict__ bes, int* __restrict__ bed, int* __restrict__ bjo){
  __shared__ int lcnt[8];
  __shared__ int lbase[8];
  if (threadIdx.x < 8) lcnt[threadIdx.x] = 0;
  __syncthreads();
  int j = blockIdx.x*256 + threadIdx.x;
  int b = 0, r = 0, s = 0, d = 0;
  bool act = (j < NE);
  if (act){
    s = src_of_j[j]; d = dst_csr[j];
    b = d / BW;
    r = atomicAdd(&lcnt[b], 1);
  }
  __syncthreads();
  if (threadIdx.x < 8) lbase[threadIdx.x] = atomicAdd(&bcur[threadIdx.x], lcnt[threadIdx.x]);
  __syncthreads();
  if (act){
    int pos = lbase[b] + r;
    bes[pos] = s; bed[pos] = d; bjo[pos] = j;
  }
}

// ---------- weight transpose + f16 convert ----------
__launch_bounds__(256)
__global__ void k_prepw(const float* __restrict__ W0, const float* __restrict__ W1,
                        const float* __restrict__ Wm1, _Float16* __restrict__ Wt){
  int idx = blockIdx.x*256 + threadIdx.x;      // mat(2b) | n(7b) | k(7b)
  if (idx >= 4*128*128) return;
  int mat = idx >> 14, rem = idx & 16383;
  int n = rem >> 7, k = rem & 127;
  const float* src = (mat == 0) ? W0 : (mat == 1) ? W1 : (mat == 2) ? Wm1 : (Wm1 + 128*128);
  Wt[idx] = (_Float16)src[k*128 + n];
}

// ---------- structural reward lookup table r_str(deg_out, deg_in), bs2 folded ----------
__launch_bounds__(256)
__global__ void k_strtab(const float* __restrict__ Ws1, const float* __restrict__ bs1,
                         const float* __restrict__ ws2, const float* __restrict__ bs2,
                         float* __restrict__ tab){
  int idx = blockIdx.x*256 + threadIdx.x;
  if (idx >= 128*128) return;
  float du = (float)(idx >> 7), di = (float)(idx & 127);
  float lo = log1pf(du), li = log1pf(di);
  float acc = 0.f;
  for (int c = 0; c < 128; ++c){
    float z = du*Ws1[c] + di*Ws1[128+c] + lo*Ws1[256+c] + li*Ws1[384+c] + bs1[c];
    acc += fmaxf(z, 0.f)*ws2[c];
  }
  tab[idx] = acc + bs2[0];
}

// ---------- triple-output MFMA GEMM + attention-logit epilogue ----------
// Computes A@Bt0 (attention proj: al epilogue, optional H store), A@Bt1 (+bm1 -> U01),
// A@Bt2 (-> V01). U01/V01 rows are [hop0 | hop1] interleaved (256 elems).
template<int AF16, int SECOND>
__launch_bounds__(256)
__global__ void k_gemm3(const void* __restrict__ Ap,
                        const _Float16* __restrict__ Bt0, const _Float16* __restrict__ Bt1,
                        const _Float16* __restrict__ Bt2,
                        const float* __restrict__ bm1,
                        const float* __restrict__ a_s, const float* __restrict__ a_d,
                        _Float16* __restrict__ Hout, _Float16* __restrict__ U01,
                        _Float16* __restrict__ V01,
                        float* __restrict__ alS, float* __restrict__ alD, int M){
  int wv = threadIdx.x >> 6, lane = threadIdx.x & 63;
  int m = lane & 15, q = lane >> 4;
  int row = blockIdx.x*64 + wv*16 + m;
  int arow = (row < M) ? row : (M-1);
  half8v af[4];
  if (AF16){
    const half8v* Ar = (const half8v*)((const _Float16*)Ap + (size_t)arow*128);
    #pragma unroll
    for (int kt = 0; kt < 4; ++kt) af[kt] = Ar[kt*4 + q];
  } else {
    const float* Ar = (const float*)Ap + (size_t)arow*128;
    #pragma unroll
    for (int kt = 0; kt < 4; ++kt){
      const float4* f = (const float4*)(Ar + kt*32 + q*8);
      float4 a0 = f[0], a1 = f[1];
      half8v h;
      h[0]=(_Float16)a0.x; h[1]=(_Float16)a0.y; h[2]=(_Float16)a0.z; h[3]=(_Float16)a0.w;
      h[4]=(_Float16)a1.x; h[5]=(_Float16)a1.y; h[6]=(_Float16)a1.z; h[7]=(_Float16)a1.w;
      af[kt] = h;
    }
  }
  floatx4 acc0[8], acc1[8], acc2[8];
  #pragma unroll
  for (int ct = 0; ct < 8; ++ct){
    #pragma unroll
    for (int r = 0; r < 4; ++r){ acc0[ct][r]=0.f; acc1[ct][r]=0.f; acc2[ct][r]=0.f; }
  }
  #pragma unroll
  for (int ct = 0; ct < 8; ++ct){
    const half8v* Br0 = (const half8v*)(Bt0 + (size_t)(ct*16 + m)*128);
    const half8v* Br1 = (const half8v*)(Bt1 + (size_t)(ct*16 + m)*128);
    const half8v* Br2 = (const half8v*)(Bt2 + (size_t)(ct*16 + m)*128);
    #pragma unroll
    for (int kt = 0; kt < 4; ++kt){
      acc0[ct] = __builtin_amdgcn_mfma_f32_16x16x32_f16(af[kt], Br0[kt*4 + q], acc0[ct], 0, 0, 0);
      acc1[ct] = __builtin_amdgcn_mfma_f32_16x16x32_f16(af[kt], Br1[kt*4 + q], acc1[ct], 0, 0, 0);
      acc2[ct] = __builtin_amdgcn_mfma_f32_16x16x32_f16(af[kt], Br2[kt*4 + q], acc2[ct], 0, 0, 0);
    }
  }
  int rb = blockIdx.x*64 + wv*16 + q*4;
  // attention-logit epilogue from fp32 acc0: head = ct, in-head dim = m
  #pragma unroll
  for (int ct = 0; ct < 8; ++ct){
    float cs = a_s[ct*16 + m], cd = a_d[ct*16 + m];
    #pragma unroll
    for (int r = 0; r < 4; ++r){
      float ps = acc0[ct][r]*cs, pd = acc0[ct][r]*cd;
      #pragma unroll
      for (int off = 1; off < 16; off <<= 1){
        ps += __shfl_xor(ps, off, 64);
        pd += __shfl_xor(pd, off, 64);
      }
      int rr = rb + r;
      if (m == 0 && rr < M){ alS[rr*8 + ct] = ps; alD[rr*8 + ct] = pd; }
    }
  }
  // stores
  #pragma unroll
  for (int ct = 0; ct < 8; ++ct){
    int col = ct*16 + m;
    float bv = bm1[col];
    #pragma unroll
    for (int r = 0; r < 4; ++r){
      int rr = rb + r;
      if (rr < M){
        if (SECOND == 0) Hout[(size_t)rr*128 + col] = (_Float16)acc0[ct][r];
        U01[(size_t)rr*256 + SECOND*128 + col] = (_Float16)(acc1[ct][r] + bv);
        V01[(size_t)rr*256 + SECOND*128 + col] = (_Float16)acc2[ct][r];
      }
    }
  }
}

// ---------- fused layer-1: per-dst softmax + head-mean + aggregation + elu ----------
__launch_bounds__(256)
__global__ void k_l1attagg(const int* __restrict__ row_d, const int* __restrict__ src_dord,
                           const int* __restrict__ rs_dord,
                           const float* __restrict__ alS, const float* __restrict__ alD,
                           const _Float16* __restrict__ H,
                           float* __restrict__ a_csr, _Float16* __restrict__ h1){
  int node = blockIdx.x*4 + (threadIdx.x >> 6);
  if (node >= NN) return;
  int lane = threadIdx.x & 63;
  int j0 = row_d[node], j1 = row_d[node+1];
  if (j0 == j1){
    half2v z; z[0] = (_Float16)0; z[1] = (_Float16)0;
    ((half2v*)(h1 + (size_t)node*128))[lane] = z;
    return;
  }
  int head = lane & 7, slot = lane >> 3;
  float ad = alD[node*8 + head];
  float m = -INFINITY, ssum = 0.f;
  for (int j = j0 + slot; j < j1; j += 8){
    int s = src_dord[j];
    float z = alS[s*8 + head] + ad;
    z = (z >= 0.f) ? z : 0.2f*z;
    float mn = fmaxf(m, z);
    ssum = sc_(ssum, m, mn) + expf(z - mn);
    m = mn;
  }
  #pragma unroll
  for (int off = 8; off < 64; off <<= 1){
    float mo = __shfl_xor(m, off, 64);
    float so = __shfl_xor(ssum, off, 64);
    float mn = fmaxf(m, mo);
    ssum = sc_(ssum, m, mn) + sc_(so, mo, mn);
    m = mn;
  }
  float inv_s = 1.f / ssum;
  // phase 2: head-mean attention -> acsr (src-CSR slot via rs_dord)
  for (int j = j0 + slot; j < j1; j += 8){
    int s = src_dord[j];
    float z = alS[s*8 + head] + ad;
    z = (z >= 0.f) ? z : 0.2f*z;
    float a = expf(z - m) * inv_s;
    float asum = a;
    asum += __shfl_xor(asum, 1, 64);
    asum += __shfl_xor(asum, 2, 64);
    asum += __shfl_xor(asum, 4, 64);
    if (head == 0) a_csr[rs_dord[j]] = asum * 0.125f;
  }
  // phase 3: aggregation; lane covers dims [2*lane, 2*lane+1], head = lane>>3
  int h2 = lane >> 3;
  float m2 = __shfl(m, h2, 64);
  float is2 = __shfl(inv_s, h2, 64);
  float ad2 = alD[node*8 + h2];
  float ax = 0.f, ay = 0.f;
  const half2v* Hv = (const half2v*)H;
  for (int j = j0; j < j1; ++j){
    int s = src_dord[j];
    float z = alS[s*8 + h2] + ad2;
    z = (z >= 0.f) ? z : 0.2f*z;
    float a = expf(z - m2) * is2;
    half2v hv = Hv[(size_t)s*64 + lane];
    ax += a*(float)hv[0];
    ay += a*(float)hv[1];
  }
  ax = (ax > 0.f) ? ax : expm1f(ax);
  ay = (ay > 0.f) ? ay : expm1f(ay);
  half2v o; o[0] = (_Float16)ax; o[1] = (_Float16)ay;
  ((half2v*)(h1 + (size_t)node*128))[lane] = o;
}

// ---------- layer-2 per-dst softmax, head-mean only ----------
__launch_bounds__(256)
__global__ void k_attsm2(const int* __restrict__ row_d, const int* __restrict__ src_dord,
                         const int* __restrict__ rs_dord,
                         const float* __restrict__ alS, const float* __restrict__ alD,
                         float* __restrict__ a_csr){
  int node = blockIdx.x*4 + (threadIdx.x >> 6);
  if (node >= NN) return;
  int lane = threadIdx.x & 63;
  int j0 = row_d[node], j1 = row_d[node+1];
  if (j0 == j1) return;
  int head = lane & 7, slot = lane >> 3;
  float ad = alD[node*8 + head];
  float m = -INFINITY, ssum = 0.f;
  for (int j = j0 + slot; j < j1; j += 8){
    int s = src_dord[j];
    float z = alS[s*8 + head] + ad;
    z = (z >= 0.f) ? z : 0.2f*z;
    float mn = fmaxf(m, z);
    ssum = sc_(ssum, m, mn) + expf(z - mn);
    m = mn;
  }
  #pragma unroll
  for (int off = 8; off < 64; off <<= 1){
    float mo = __shfl_xor(m, off, 64);
    float so = __shfl_xor(ssum, off, 64);
    float mn = fmaxf(m, mo);
    ssum = sc_(ssum, m, mn) + sc_(so, mo, mn);
    m = mn;
  }
  float inv_s = 1.f / ssum;
  for (int j = j0 + slot; j < j1; j += 8){
    int s = src_dord[j];
    float z = alS[s*8 + head] + ad;
    z = (z >= 0.f) ? z : 0.2f*z;
    float a = expf(z - m) * inv_s;
    float asum = a;
    asum += __shfl_xor(asum, 1, 64);
    asum += __shfl_xor(asum, 2, 64);
    asum += __shfl_xor(asum, 4, 64);
    if (head == 0) a_csr[rs_dord[j]] = asum * 0.125f;
  }
}

// ---------- bucketed per-edge rewards; 16 lanes/edge; XCD-pinned V-slices ----------
__launch_bounds__(256)
__global__ void k_edge4(const int* __restrict__ boff,
                        const int* __restrict__ bes, const int* __restrict__ bed,
                        const int* __restrict__ bjo,
                        const unsigned char* __restrict__ d8o, const unsigned char* __restrict__ d8i,
                        const float* __restrict__ tab,
                        const _Float16* __restrict__ U01, const _Float16* __restrict__ V01,
                        const float* __restrict__ wm2, const float* __restrict__ bm2,
                        const float* __restrict__ lam1,
                        float* __restrict__ rcsr0, float* __restrict__ rcsr1){
  __shared__ _Float16 wml[128];
  if (threadIdx.x < 128) wml[threadIdx.x] = (_Float16)wm2[threadIdx.x];
  __syncthreads();
  int bucket = blockIdx.x & 7, chunk = blockIdx.x >> 3;
  int j2base = boff[bucket];
  int cnt = boff[bucket+1] - j2base;
  int t = threadIdx.x & 15, eg = threadIdx.x >> 4;
  const half8v* wl = (const half8v*)wml;
  half8v w = wl[t];
  float lam = lam1[0], bb2 = bm2[0];
  for (int i = chunk*16 + eg; i < cnt; i += BPB*16){
    int j2 = j2base + i;
    int s = bes[j2], d = bed[j2], jo = bjo[j2];
    const half8v* ur = (const half8v*)(U01 + (size_t)s*256);
    const half8v* vr = (const half8v*)(V01 + (size_t)d*256);
    half8v a = ur[t] + vr[t];          // hop 0 (bm1 folded into U)
    half8v b = ur[16 + t] + vr[16 + t]; // hop 1
    #pragma unroll
    for (int k = 0; k < 8; ++k){
      a[k] = (a[k] > (_Float16)0) ? a[k] : (_Float16)0;
      b[k] = (b[k] > (_Float16)0) ? b[k] : (_Float16)0;
    }
    float r0 = 0.f, r1 = 0.f;
    #pragma unroll
    for (int c = 0; c < 4; ++c){
      half2v aa = {a[2*c], a[2*c+1]};
      half2v bb = {b[2*c], b[2*c+1]};
      half2v ww = {w[2*c], w[2*c+1]};
      r0 = dot2acc(aa, ww, r0);
      r1 = dot2acc(bb, ww, r1);
    }
    red16(r0); red16(r1);
    if (t == 0){
      float rstr = tab[((int)d8o[s] << 7) | (int)d8i[d]];
      rcsr0[jo] = rstr + lam*(r0 + bb2);
      rcsr1[jo] = rstr + lam*(r1 + bb2);
    }
  }
}

// ---------- soft value iteration V-update (both hops), 16 lanes/node ----------
__launch_bounds__(256)
__global__ void k_svi(const int* __restrict__ row_s, const int* __restrict__ dst_csr,
                      const float* __restrict__ r0, const float* __restrict__ r1,
                      const float* __restrict__ V0in, const float* __restrict__ V1in,
                      float* __restrict__ out0, float* __restrict__ out1){
  int node = blockIdx.x*16 + (threadIdx.x >> 4);
  if (node >= NN) return;
  int t = threadIdx.x & 15;
  int j0 = row_s[node], j1 = row_s[node+1];
  if (j0 == j1){
    if (t == 0){ out0[node] = 0.f; out1[node] = 0.f; }
    return;
  }
  float m0 = -INFINITY, s0 = 0.f, m1 = -INFINITY, s1 = 0.f;
  for (int j = j0 + t; j < j1; j += 16){
    int d = dst_csr[j];
    float q0 = (r0[j] + V0in[d]) * INVB;
    float q1 = (r1[j] + V1in[d]) * INVB;
    float mn0 = fmaxf(m0, q0);
    s0 = sc_(s0, m0, mn0) + expf(q0 - mn0); m0 = mn0;
    float mn1 = fmaxf(m1, q1);
    s1 = sc_(s1, m1, mn1) + expf(q1 - mn1); m1 = mn1;
  }
  lse16(m0, s0); lse16(m1, s1);
  if (t == 0){
    out0[node] = BETAF*(logf(s0) + m0);
    out1[node] = BETAF*(logf(s1) + m1);
  }
}

// ---------- fused: logz + obs-lse + NLL + KL score; 16 lanes/node ----------
__launch_bounds__(256)
__global__ void k_final2(const int* __restrict__ row_s, const int* __restrict__ dst_csr,
                         const float* __restrict__ a0, const float* __restrict__ a1,
                         const float* __restrict__ r0, const float* __restrict__ r1,
                         const float* __restrict__ V0, const float* __restrict__ V1,
                         float* __restrict__ out, float* __restrict__ partial){
  int node = blockIdx.x*16 + (threadIdx.x >> 4);
  int t = threadIdx.x & 15;
  float nll = 0.f;
  if (node < NN){
    int j0 = row_s[node], j1 = row_s[node+1];
    if (j0 == j1){
      if (t == 0) out[1 + node] = 0.f;
    } else {
      float mq0=-INFINITY, sq0=0.f, mq1=-INFINITY, sq1=0.f;
      float ma0=-INFINITY, sa0=0.f, ma1=-INFINITY, sa1=0.f;
      for (int j = j0 + t; j < j1; j += 16){
        int d = dst_csr[j];
        float q0 = (r0[j] + V0[d]) * INVB;
        float q1 = (r1[j] + V1[d]) * INVB;
        float la0 = logf(a0[j] + 1e-12f);
        float la1 = logf(a1[j] + 1e-12f);
        float mn;
        mn = fmaxf(mq0, q0); sq0 = sc_(sq0, mq0, mn) + expf(q0 - mn); mq0 = mn;
        mn = fmaxf(mq1, q1); sq1 = sc_(sq1, mq1, mn) + expf(q1 - mn); mq1 = mn;
        mn = fmaxf(ma0, la0); sa0 = sc_(sa0, ma0, mn) + expf(la0 - mn); ma0 = mn;
        mn = fmaxf(ma1, la1); sa1 = sc_(sa1, ma1, mn) + expf(la1 - mn); ma1 = mn;
      }
      lse16(mq0, sq0); lse16(mq1, sq1); lse16(ma0, sa0); lse16(ma1, sa1);
      float L0 = logf(sq0) + mq0, L1 = logf(sq1) + mq1;
      float O0 = logf(sa0) + ma0, O1 = logf(sa1) + ma1;
      float sca = 0.f;
      for (int j = j0 + t; j < j1; j += 16){
        int d = dst_csr[j];
        float la0 = logf(a0[j] + 1e-12f);
        float lp0 = la0 - O0;
        float p0 = expf(lp0);
        float ls0 = (r0[j] + V0[d]) * INVB - L0;
        nll -= p0 * ls0;
        sca += p0 * (lp0 - ls0);
        float la1 = logf(a1[j] + 1e-12f);
        float lp1 = la1 - O1;
        float p1 = expf(lp1);
        float ls1 = (r1[j] + V1[d]) * INVB - L1;
        nll -= p1 * ls1;
        sca += p1 * (lp1 - ls1);
      }
      red16(sca);
      if (t == 0) out[1 + node] = sca;
    }
  }
  #pragma unroll
  for (int off = 1; off < 64; off <<= 1) nll += __shfl_xor(nll, off, 64);
  __shared__ float wsum[4];
  if ((threadIdx.x & 63) == 0) wsum[threadIdx.x >> 6] = nll;
  __syncthreads();
  if (threadIdx.x == 0) partial[blockIdx.x] = wsum[0]+wsum[1]+wsum[2]+wsum[3];
}

__launch_bounds__(256)
__global__ void k_nllred(const float* __restrict__ partial, int np, float* __restrict__ out){
  float s = 0.f;
  for (int i = threadIdx.x; i < np; i += 256) s += partial[i];
  #pragma unroll
  for (int off = 1; off < 64; off <<= 1) s += __shfl_xor(s, off, 64);
  __shared__ float wsum[4];
  if ((threadIdx.x & 63) == 0) wsum[threadIdx.x >> 6] = s;
  __syncthreads();
  if (threadIdx.x == 0) out[0] = (wsum[0]+wsum[1]+wsum[2]+wsum[3]) * (1.f/NN);
}

// =======================================================================
extern "C" void kernel_launch(void* const* d_in, const int* in_sizes, int n_in,
                              void* d_out, int out_size, void* d_ws, size_t ws_size,
                              hipStream_t stream){
  const float* x    = (const float*)d_in[0];
  const int*   ei   = (const int*)d_in[1];
  const float* W0   = (const float*)d_in[2];
  const float* as0  = (const float*)d_in[3];
  const float* ad0  = (const float*)d_in[4];
  const float* W1   = (const float*)d_in[5];
  const float* as1  = (const float*)d_in[6];
  const float* ad1  = (const float*)d_in[7];
  const float* Ws1  = (const float*)d_in[8];
  const float* bs1  = (const float*)d_in[9];
  const float* ws2  = (const float*)d_in[10];
  const float* bs2  = (const float*)d_in[11];
  const float* Wm1  = (const float*)d_in[12];
  const float* bm1  = (const float*)d_in[13];
  const float* wm2  = (const float*)d_in[14];
  const float* bm2  = (const float*)d_in[15];
  const float* lam1 = (const float*)d_in[16];
  float* out = (float*)d_out;

  char* p = (char*)d_ws;
  auto alloc = [&](size_t bytes)->void*{
    void* r = (void*)p;
    p += (bytes + 255) & ~(size_t)255;
    return r;
  };
  _Float16* Hh   = (_Float16*)alloc((size_t)NN*128*2);   // layer-1 projection (f16)
  _Float16* h1f  = (_Float16*)alloc((size_t)NN*128*2);
  _Float16* U01  = (_Float16*)alloc((size_t)NN*256*2);   // [u0 | u1] per node
  _Float16* V01  = (_Float16*)alloc((size_t)NN*256*2);   // [v0 | v1] per node
  _Float16* Wt   = (_Float16*)alloc((size_t)4*128*128*2);
  float* tab     = (float*)alloc((size_t)128*128*4);
  int*   src_of_j= (int*)alloc((size_t)NE*4);
  int*   dst_csr = (int*)alloc((size_t)NE*4);
  int*   src_dord= (int*)alloc((size_t)NE*4);
  int*   rs_dord = (int*)alloc((size_t)NE*4);
  int*   bes     = (int*)alloc((size_t)NE*4);
  int*   bed     = (int*)alloc((size_t)NE*4);
  int*   bjo     = (int*)alloc((size_t)NE*4);
  int*   row_s   = (int*)alloc((size_t)(NN+1)*4);
  int*   row_d   = (int*)alloc((size_t)(NN+1)*4);
  int*   cur_s   = (int*)alloc((size_t)NN*4);
  int*   cur_d   = (int*)alloc((size_t)NN*4);
  int*   partA   = (int*)alloc(256*4);
  int*   partB   = (int*)alloc(256*4);
  int*   bcnt    = (int*)alloc(16*4);
  int*   boff    = (int*)alloc(16*4);
  int*   bcur    = (int*)alloc(16*4);
  unsigned char* d8o = (unsigned char*)alloc(NN);
  unsigned char* d8i = (unsigned char*)alloc(NN);
  float* alS     = (float*)alloc((size_t)NN*8*4);
  float* alD     = (float*)alloc((size_t)NN*8*4);
  float* acsr0   = (float*)alloc((size_t)NE*4);
  float* acsr1   = (float*)alloc((size_t)NE*4);
  float* rcsr0   = (float*)alloc((size_t)NE*4);
  float* rcsr1   = (float*)alloc((size_t)NE*4);
  float* V0a = (float*)alloc((size_t)NN*4);
  float* V0b = (float*)alloc((size_t)NN*4);
  float* V1a = (float*)alloc((size_t)NN*4);
  float* V1b = (float*)alloc((size_t)NN*4);
  float* nllpart = (float*)alloc((size_t)4*((NN+15)/16 + 1));

  _Float16* W0t = Wt;
  _Float16* W1t = Wt + 128*128;
  _Float16* Wut = Wt + 2*128*128;
  _Float16* Wvt = Wt + 3*128*128;

  const int G_E    = (NE + 255)/256;      // 3125
  const int G_gemm = (NN + 63)/64;        // 782
  const int G_n4   = (NN + 3)/4;          // 12500
  const int G_n16  = (NN + 15)/16;        // 3125
  const int NPART  = (NN + 255)/256;      // 196

  // ---- CSR build ----
  hipMemsetAsync(cur_s, 0, (size_t)NN*4, stream);
  hipMemsetAsync(cur_d, 0, (size_t)NN*4, stream);
  hipMemsetAsync(bcnt, 0, 16*4, stream);
  k_hist<<<G_E, 256, 0, stream>>>(ei, cur_s, cur_d);
  k_scan_a<<<dim3(NPART,2), 256, 0, stream>>>(cur_s, cur_d, row_s, row_d, partA, partB, NN);
  k_scan_b<<<dim3(1,2), 256, 0, stream>>>(partA, partB, NPART);
  k_scan_c<<<dim3(NPART,2), 256, 0, stream>>>(row_s, row_d, cur_s, cur_d, partA, partB, NN);
  k_scatter<<<G_E, 256, 0, stream>>>(ei, cur_s, cur_d, src_of_j, dst_csr, src_dord, rs_dord);
  k_deg<<<(NN+255)/256, 256, 0, stream>>>(row_s, row_d, d8o, d8i);

  // ---- dst-bucketed edge list (XCD L2 slicing) ----
  k_bhist<<<G_E, 256, 0, stream>>>(dst_csr, bcnt);
  k_bscan<<<1, 64, 0, stream>>>(bcnt, boff, bcur);
  k_bscatter<<<G_E, 256, 0, stream>>>(src_of_j, dst_csr, bcur, bes, bed, bjo);

  // ---- weight prep + structural table ----
  k_prepw<<<(4*128*128+255)/256, 256, 0, stream>>>(W0, W1, Wm1, Wt);
  k_strtab<<<(128*128+255)/256, 256, 0, stream>>>(Ws1, bs1, ws2, bs2, tab);

  // ---- layer 1: x @ {W0, Wu, Wv} + al epilogue ----
  k_gemm3<0,0><<<G_gemm, 256, 0, stream>>>(x, W0t, Wut, Wvt, bm1, as0, ad0,
                                           Hh, U01, V01, alS, alD, NN);
  k_l1attagg<<<G_n4, 256, 0, stream>>>(row_d, src_dord, rs_dord, alS, alD, Hh, acsr0, h1f);

  // ---- layer 2: h1 @ {W1, Wu, Wv} + al epilogue (no H store) ----
  k_gemm3<1,1><<<G_gemm, 256, 0, stream>>>(h1f, W1t, Wut, Wvt, bm1, as1, ad1,
                                           nullptr, U01, V01, alS, alD, NN);
  k_attsm2<<<G_n4, 256, 0, stream>>>(row_d, src_dord, rs_dord, alS, alD, acsr1);

  // ---- bucketed per-edge rewards ----
  k_edge4<<<8*BPB, 256, 0, stream>>>(boff, bes, bed, bjo, d8o, d8i, tab,
                                     U01, V01, wm2, bm2, lam1, rcsr0, rcsr1);

  // ---- soft value iteration ----
  hipMemsetAsync(V0a, 0, (size_t)NN*4, stream);
  hipMemsetAsync(V1a, 0, (size_t)NN*4, stream);
  float* v0i = V0a; float* v0o = V0b;
  float* v1i = V1a; float* v1o = V1b;
  for (int it = 0; it < 5; ++it){
    k_svi<<<G_n16, 256, 0, stream>>>(row_s, dst_csr, rcsr0, rcsr1, v0i, v1i, v0o, v1o);
    float* t;
    t = v0i; v0i = v0o; v0o = t;
    t = v1i; v1i = v1o; v1o = t;
  }

  // ---- fused logz + obs-lse + loss + score ----
  k_final2<<<G_n16, 256, 0, stream>>>(row_s, dst_csr, acsr0, acsr1, rcsr0, rcsr1,
                                      v0i, v1i, out, nllpart);
  k_nllred<<<1, 256, 0, stream>>>(nllpart, G_n16, out);
}

// Round 5
// 709.973 us; speedup vs baseline: 1.1754x; 1.1754x over previous
//
#include <hip/hip_runtime.h>
#include <math.h>

#define NN 50000
#define NE 800000
#define BETAF 0.1f
#define INVB 10.0f

typedef _Float16 half8v __attribute__((ext_vector_type(8)));
typedef _Float16 half2v __attribute__((ext_vector_type(2)));
typedef float floatx4 __attribute__((ext_vector_type(4)));

// ---------- helpers ----------
__device__ __forceinline__ float sc_(float s, float m, float mn){
  return (s == 0.f) ? 0.f : s * expf(m - mn);
}
__device__ __forceinline__ void red16(float& v){
  v += __shfl_xor(v, 1, 64); v += __shfl_xor(v, 2, 64);
  v += __shfl_xor(v, 4, 64); v += __shfl_xor(v, 8, 64);
}
__device__ __forceinline__ void lse16(float& m, float& s){
  #pragma unroll
  for (int off = 1; off < 16; off <<= 1){
    float mo = __shfl_xor(m, off, 64), so = __shfl_xor(s, off, 64);
    float mn = fmaxf(m, mo);
    s = sc_(s, m, mn) + sc_(so, mo, mn); m = mn;
  }
}
__device__ __forceinline__ float dot2acc(half2v a, half2v b, float c){
#if __has_builtin(__builtin_amdgcn_fdot2)
  return __builtin_amdgcn_fdot2(a, b, c, false);
#else
  return c + (float)a[0]*(float)b[0] + (float)a[1]*(float)b[1];
#endif
}

// ---------- degree histogram ----------
__launch_bounds__(256)
__global__ void k_hist(const int* __restrict__ ei, int* __restrict__ cs, int* __restrict__ cd){
  int e = blockIdx.x*256 + threadIdx.x;
  if (e >= NE) return;
  atomicAdd(&cs[ei[e]], 1);
  atomicAdd(&cd[ei[NE + e]], 1);
}

// ---------- 3-phase exclusive scan ----------
__launch_bounds__(256)
__global__ void k_scan_a(const int* __restrict__ inA, const int* __restrict__ inB,
                         int* __restrict__ outA, int* __restrict__ outB,
                         int* __restrict__ partA, int* __restrict__ partB, int n){
  const int* in = blockIdx.y ? inB : inA;
  int* out = blockIdx.y ? outB : outA;
  int* part = blockIdx.y ? partB : partA;
  int i = blockIdx.x*256 + threadIdx.x;
  int v = (i < n) ? in[i] : 0;
  int lane = threadIdx.x & 63, wid = threadIdx.x >> 6;
  int x = v;
  #pragma unroll
  for (int off = 1; off < 64; off <<= 1){
    int t = __shfl_up(x, off, 64);
    if (lane >= off) x += t;
  }
  __shared__ int wsum[4];
  if (lane == 63) wsum[wid] = x;
  __syncthreads();
  int base = 0;
  #pragma unroll
  for (int w = 0; w < 4; ++w) if (w < wid) base += wsum[w];
  if (i < n) out[i] = base + x - v;
  if (threadIdx.x == 255) part[blockIdx.x] = base + x;
}

__launch_bounds__(256)
__global__ void k_scan_b(int* __restrict__ partA, int* __restrict__ partB, int np){
  int* part = blockIdx.y ? partB : partA;
  int i = threadIdx.x;
  int v = (i < np) ? part[i] : 0;
  int lane = threadIdx.x & 63, wid = threadIdx.x >> 6;
  int x = v;
  #pragma unroll
  for (int off = 1; off < 64; off <<= 1){
    int t = __shfl_up(x, off, 64);
    if (lane >= off) x += t;
  }
  __shared__ int wsum[4];
  if (lane == 63) wsum[wid] = x;
  __syncthreads();
  int base = 0;
  #pragma unroll
  for (int w = 0; w < 4; ++w) if (w < wid) base += wsum[w];
  if (i < np) part[i] = base + x - v;
}

__launch_bounds__(256)
__global__ void k_scan_c(int* __restrict__ outA, int* __restrict__ outB,
                         int* __restrict__ curA, int* __restrict__ curB,
                         const int* __restrict__ partA, const int* __restrict__ partB, int n){
  int* out = blockIdx.y ? outB : outA;
  int* cur = blockIdx.y ? curB : curA;
  const int* part = blockIdx.y ? partB : partA;
  int i = blockIdx.x*256 + threadIdx.x;
  if (i < n){
    int f = out[i] + part[blockIdx.x];
    out[i] = f;
    cur[i] = f;
  }
  if (blockIdx.x == 0 && threadIdx.x == 0) out[n] = NE;
}

// ---------- CSR scatter ----------
__launch_bounds__(256)
__global__ void k_scatter(const int* __restrict__ ei, int* __restrict__ cur_s, int* __restrict__ cur_d,
                          int* __restrict__ src_of_j, int* __restrict__ dst_csr,
                          int* __restrict__ src_dord, int* __restrict__ rs_dord){
  int e = blockIdx.x*256 + threadIdx.x;
  if (e >= NE) return;
  int s = ei[e], d = ei[NE + e];
  int js = atomicAdd(&cur_s[s], 1);
  src_of_j[js] = s;
  dst_csr[js] = d;
  int jd = atomicAdd(&cur_d[d], 1);
  src_dord[jd] = s;
  rs_dord[jd] = js;
}

// ---------- clamped uint8 degrees ----------
__launch_bounds__(256)
__global__ void k_deg(const int* __restrict__ row_s, const int* __restrict__ row_d,
                      unsigned char* __restrict__ d8o, unsigned char* __restrict__ d8i){
  int n = blockIdx.x*256 + threadIdx.x;
  if (n >= NN) return;
  int a = row_s[n+1] - row_s[n];
  int b = row_d[n+1] - row_d[n];
  d8o[n] = (unsigned char)(a > 127 ? 127 : a);
  d8i[n] = (unsigned char)(b > 127 ? 127 : b);
}

// ---------- weight transpose + f16 convert ----------
__launch_bounds__(256)
__global__ void k_prepw(const float* __restrict__ W0, const float* __restrict__ W1,
                        const float* __restrict__ Wm1, _Float16* __restrict__ Wt){
  int idx = blockIdx.x*256 + threadIdx.x;      // mat(2b) | n(7b) | k(7b)
  if (idx >= 4*128*128) return;
  int mat = idx >> 14, rem = idx & 16383;
  int n = rem >> 7, k = rem & 127;
  const float* src = (mat == 0) ? W0 : (mat == 1) ? W1 : (mat == 2) ? Wm1 : (Wm1 + 128*128);
  Wt[idx] = (_Float16)src[k*128 + n];
}

// ---------- structural reward lookup table r_str(deg_out, deg_in), bs2 folded ----------
__launch_bounds__(256)
__global__ void k_strtab(const float* __restrict__ Ws1, const float* __restrict__ bs1,
                         const float* __restrict__ ws2, const float* __restrict__ bs2,
                         float* __restrict__ tab){
  int idx = blockIdx.x*256 + threadIdx.x;
  if (idx >= 128*128) return;
  float du = (float)(idx >> 7), di = (float)(idx & 127);
  float lo = log1pf(du), li = log1pf(di);
  float acc = 0.f;
  for (int c = 0; c < 128; ++c){
    float z = du*Ws1[c] + di*Ws1[128+c] + lo*Ws1[256+c] + li*Ws1[384+c] + bs1[c];
    acc += fmaxf(z, 0.f)*ws2[c];
  }
  tab[idx] = acc + bs2[0];
}

// ---------- triple-output MFMA GEMM + attention-logit epilogue ----------
template<int AF16, int SECOND>
__launch_bounds__(256)
__global__ void k_gemm3(const void* __restrict__ Ap,
                        const _Float16* __restrict__ Bt0, const _Float16* __restrict__ Bt1,
                        const _Float16* __restrict__ Bt2,
                        const float* __restrict__ bm1,
                        const float* __restrict__ a_s, const float* __restrict__ a_d,
                        _Float16* __restrict__ Hout, _Float16* __restrict__ U01,
                        _Float16* __restrict__ V01,
                        float* __restrict__ alS, float* __restrict__ alD, int M){
  int wv = threadIdx.x >> 6, lane = threadIdx.x & 63;
  int m = lane & 15, q = lane >> 4;
  int row = blockIdx.x*64 + wv*16 + m;
  int arow = (row < M) ? row : (M-1);
  half8v af[4];
  if (AF16){
    const half8v* Ar = (const half8v*)((const _Float16*)Ap + (size_t)arow*128);
    #pragma unroll
    for (int kt = 0; kt < 4; ++kt) af[kt] = Ar[kt*4 + q];
  } else {
    const float* Ar = (const float*)Ap + (size_t)arow*128;
    #pragma unroll
    for (int kt = 0; kt < 4; ++kt){
      const float4* f = (const float4*)(Ar + kt*32 + q*8);
      float4 a0 = f[0], a1 = f[1];
      half8v h;
      h[0]=(_Float16)a0.x; h[1]=(_Float16)a0.y; h[2]=(_Float16)a0.z; h[3]=(_Float16)a0.w;
      h[4]=(_Float16)a1.x; h[5]=(_Float16)a1.y; h[6]=(_Float16)a1.z; h[7]=(_Float16)a1.w;
      af[kt] = h;
    }
  }
  floatx4 acc0[8], acc1[8], acc2[8];
  #pragma unroll
  for (int ct = 0; ct < 8; ++ct){
    #pragma unroll
    for (int r = 0; r < 4; ++r){ acc0[ct][r]=0.f; acc1[ct][r]=0.f; acc2[ct][r]=0.f; }
  }
  #pragma unroll
  for (int ct = 0; ct < 8; ++ct){
    const half8v* Br0 = (const half8v*)(Bt0 + (size_t)(ct*16 + m)*128);
    const half8v* Br1 = (const half8v*)(Bt1 + (size_t)(ct*16 + m)*128);
    const half8v* Br2 = (const half8v*)(Bt2 + (size_t)(ct*16 + m)*128);
    #pragma unroll
    for (int kt = 0; kt < 4; ++kt){
      acc0[ct] = __builtin_amdgcn_mfma_f32_16x16x32_f16(af[kt], Br0[kt*4 + q], acc0[ct], 0, 0, 0);
      acc1[ct] = __builtin_amdgcn_mfma_f32_16x16x32_f16(af[kt], Br1[kt*4 + q], acc1[ct], 0, 0, 0);
      acc2[ct] = __builtin_amdgcn_mfma_f32_16x16x32_f16(af[kt], Br2[kt*4 + q], acc2[ct], 0, 0, 0);
    }
  }
  int rb = blockIdx.x*64 + wv*16 + q*4;
  // attention-logit epilogue from fp32 acc0: head = ct, in-head dim = m
  #pragma unroll
  for (int ct = 0; ct < 8; ++ct){
    float cs = a_s[ct*16 + m], cd = a_d[ct*16 + m];
    #pragma unroll
    for (int r = 0; r < 4; ++r){
      float ps = acc0[ct][r]*cs, pd = acc0[ct][r]*cd;
      #pragma unroll
      for (int off = 1; off < 16; off <<= 1){
        ps += __shfl_xor(ps, off, 64);
        pd += __shfl_xor(pd, off, 64);
      }
      int rr = rb + r;
      if (m == 0 && rr < M){ alS[rr*8 + ct] = ps; alD[rr*8 + ct] = pd; }
    }
  }
  #pragma unroll
  for (int ct = 0; ct < 8; ++ct){
    int col = ct*16 + m;
    float bv = bm1[col];
    #pragma unroll
    for (int r = 0; r < 4; ++r){
      int rr = rb + r;
      if (rr < M){
        if (SECOND == 0) Hout[(size_t)rr*128 + col] = (_Float16)acc0[ct][r];
        U01[(size_t)rr*256 + SECOND*128 + col] = (_Float16)(acc1[ct][r] + bv);
        V01[(size_t)rr*256 + SECOND*128 + col] = (_Float16)acc2[ct][r];
      }
    }
  }
}

// ---------- fused per-dst softmax (+optional aggregation), LDS attn cache ----------
// wave per node; deg<=64 fast path stores z -> a in LDS, phase 3 reads a (no exp).
template<bool AGG>
__launch_bounds__(256)
__global__ void k_att(const int* __restrict__ row_d, const int* __restrict__ src_dord,
                      const int* __restrict__ rs_dord,
                      const float* __restrict__ alS, const float* __restrict__ alD,
                      const _Float16* __restrict__ H,
                      float* __restrict__ a_csr, _Float16* __restrict__ h1){
  __shared__ float zbuf[4][64*8];   // 8 KB: [wave][edge*8+head]
  int wv = threadIdx.x >> 6;
  int node = blockIdx.x*4 + wv;
  if (node >= NN) return;
  int lane = threadIdx.x & 63;
  int j0 = row_d[node], j1 = row_d[node+1];
  int deg = j1 - j0;
  if (deg == 0){
    if (AGG){
      half2v z; z[0] = (_Float16)0; z[1] = (_Float16)0;
      ((half2v*)(h1 + (size_t)node*128))[lane] = z;
    }
    return;
  }
  int head = lane & 7, slot = lane >> 3;
  float ad = alD[node*8 + head];
  float m = -INFINITY, ssum = 0.f;

  if (deg <= 64){
    // phase 1: logits -> LDS, online lse per (slot,head)
    for (int e = slot; e < deg; e += 8){
      int s = src_dord[j0 + e];
      float z = alS[s*8 + head] + ad;
      z = (z >= 0.f) ? z : 0.2f*z;
      zbuf[wv][e*8 + head] = z;
      float mn = fmaxf(m, z);
      ssum = sc_(ssum, m, mn) + expf(z - mn);
      m = mn;
    }
    #pragma unroll
    for (int off = 8; off < 64; off <<= 1){
      float mo = __shfl_xor(m, off, 64);
      float so = __shfl_xor(ssum, off, 64);
      float mn = fmaxf(m, mo);
      ssum = sc_(ssum, m, mn) + sc_(so, mo, mn);
      m = mn;
    }
    float inv_s = 1.f / ssum;
    // phase 2: z -> a in LDS (1 exp per entry), head-mean -> acsr
    for (int e = slot; e < deg; e += 8){
      float a = expf(zbuf[wv][e*8 + head] - m) * inv_s;
      zbuf[wv][e*8 + head] = a;
      float asum = a;
      asum += __shfl_xor(asum, 1, 64);
      asum += __shfl_xor(asum, 2, 64);
      asum += __shfl_xor(asum, 4, 64);
      if (head == 0) a_csr[rs_dord[j0 + e]] = asum * 0.125f;
    }
    if (AGG){
      __asm__ volatile("s_waitcnt lgkmcnt(0)" ::: "memory");  // cross-lane LDS visibility
      int h2 = lane >> 3;
      float ax = 0.f, ay = 0.f;
      const half2v* Hv = (const half2v*)H;
      for (int e = 0; e < deg; ++e){
        int s = src_dord[j0 + e];
        float a = zbuf[wv][e*8 + h2];
        half2v hv = Hv[(size_t)s*64 + lane];
        ax += a*(float)hv[0];
        ay += a*(float)hv[1];
      }
      ax = (ax > 0.f) ? ax : expm1f(ax);
      ay = (ay > 0.f) ? ay : expm1f(ay);
      half2v o; o[0] = (_Float16)ax; o[1] = (_Float16)ay;
      ((half2v*)(h1 + (size_t)node*128))[lane] = o;
    }
  } else {
    // rare fallback: recompute path (no LDS)
    for (int j = j0 + slot; j < j1; j += 8){
      int s = src_dord[j];
      float z = alS[s*8 + head] + ad;
      z = (z >= 0.f) ? z : 0.2f*z;
      float mn = fmaxf(m, z);
      ssum = sc_(ssum, m, mn) + expf(z - mn);
      m = mn;
    }
    #pragma unroll
    for (int off = 8; off < 64; off <<= 1){
      float mo = __shfl_xor(m, off, 64);
      float so = __shfl_xor(ssum, off, 64);
      float mn = fmaxf(m, mo);
      ssum = sc_(ssum, m, mn) + sc_(so, mo, mn);
      m = mn;
    }
    float inv_s = 1.f / ssum;
    for (int j = j0 + slot; j < j1; j += 8){
      int s = src_dord[j];
      float z = alS[s*8 + head] + ad;
      z = (z >= 0.f) ? z : 0.2f*z;
      float a = expf(z - m) * inv_s;
      float asum = a;
      asum += __shfl_xor(asum, 1, 64);
      asum += __shfl_xor(asum, 2, 64);
      asum += __shfl_xor(asum, 4, 64);
      if (head == 0) a_csr[rs_dord[j]] = asum * 0.125f;
    }
    if (AGG){
      int h2 = lane >> 3;
      float m2 = __shfl(m, h2*8, 64);
      float is2 = __shfl(inv_s, h2*8, 64);
      float ad2 = alD[node*8 + h2];
      float ax = 0.f, ay = 0.f;
      const half2v* Hv = (const half2v*)H;
      for (int j = j0; j < j1; ++j){
        int s = src_dord[j];
        float z = alS[s*8 + h2] + ad2;
        z = (z >= 0.f) ? z : 0.2f*z;
        float a = expf(z - m2) * is2;
        half2v hv = Hv[(size_t)s*64 + lane];
        ax += a*(float)hv[0];
        ay += a*(float)hv[1];
      }
      ax = (ax > 0.f) ? ax : expm1f(ax);
      ay = (ay > 0.f) ? ay : expm1f(ay);
      half2v o; o[0] = (_Float16)ax; o[1] = (_Float16)ay;
      ((half2v*)(h1 + (size_t)node*128))[lane] = o;
    }
  }
}

// ---------- per-edge rewards; 16 lanes/edge, src-CSR order (U L1-hot, V random) ----------
__launch_bounds__(256)
__global__ void k_edge5(const int* __restrict__ src_of_j, const int* __restrict__ dst_csr,
                        const unsigned char* __restrict__ d8o, const unsigned char* __restrict__ d8i,
                        const float* __restrict__ tab,
                        const _Float16* __restrict__ U01, const _Float16* __restrict__ V01,
                        const float* __restrict__ wm2, const float* __restrict__ bm2,
                        const float* __restrict__ lam1,
                        float* __restrict__ rcsr0, float* __restrict__ rcsr1){
  __shared__ _Float16 wml[128];
  if (threadIdx.x < 128) wml[threadIdx.x] = (_Float16)wm2[threadIdx.x];
  __syncthreads();
  int j = blockIdx.x*16 + (threadIdx.x >> 4);
  if (j >= NE) return;
  int t = threadIdx.x & 15;
  int s = src_of_j[j], d = dst_csr[j];
  const half8v* ur = (const half8v*)(U01 + (size_t)s*256);
  const half8v* vr = (const half8v*)(V01 + (size_t)d*256);
  half8v a = ur[t] + vr[t];            // hop 0 (bm1 folded into U)
  half8v b = ur[16 + t] + vr[16 + t];  // hop 1
  #pragma unroll
  for (int k = 0; k < 8; ++k){
    a[k] = (a[k] > (_Float16)0) ? a[k] : (_Float16)0;
    b[k] = (b[k] > (_Float16)0) ? b[k] : (_Float16)0;
  }
  const half8v* wl = (const half8v*)wml;
  half8v w = wl[t];
  float r0 = 0.f, r1 = 0.f;
  #pragma unroll
  for (int c = 0; c < 4; ++c){
    half2v aa = {a[2*c], a[2*c+1]};
    half2v bb = {b[2*c], b[2*c+1]};
    half2v ww = {w[2*c], w[2*c+1]};
    r0 = dot2acc(aa, ww, r0);
    r1 = dot2acc(bb, ww, r1);
  }
  red16(r0); red16(r1);
  if (t == 0){
    float rstr = tab[((int)d8o[s] << 7) | (int)d8i[d]];
    float lam = lam1[0], bb2 = bm2[0];
    rcsr0[j] = rstr + lam*(r0 + bb2);
    rcsr1[j] = rstr + lam*(r1 + bb2);
  }
}

// ---------- soft value iteration V-update (both hops), 16 lanes/node ----------
__launch_bounds__(256)
__global__ void k_svi(const int* __restrict__ row_s, const int* __restrict__ dst_csr,
                      const float* __restrict__ r0, const float* __restrict__ r1,
                      const float* __restrict__ V0in, const float* __restrict__ V1in,
                      float* __restrict__ out0, float* __restrict__ out1){
  int node = blockIdx.x*16 + (threadIdx.x >> 4);
  if (node >= NN) return;
  int t = threadIdx.x & 15;
  int j0 = row_s[node], j1 = row_s[node+1];
  if (j0 == j1){
    if (t == 0){ out0[node] = 0.f; out1[node] = 0.f; }
    return;
  }
  float m0 = -INFINITY, s0 = 0.f, m1 = -INFINITY, s1 = 0.f;
  for (int j = j0 + t; j < j1; j += 16){
    int d = dst_csr[j];
    float q0 = (r0[j] + V0in[d]) * INVB;
    float q1 = (r1[j] + V1in[d]) * INVB;
    float mn0 = fmaxf(m0, q0);
    s0 = sc_(s0, m0, mn0) + expf(q0 - mn0); m0 = mn0;
    float mn1 = fmaxf(m1, q1);
    s1 = sc_(s1, m1, mn1) + expf(q1 - mn1); m1 = mn1;
  }
  lse16(m0, s0); lse16(m1, s1);
  if (t == 0){
    out0[node] = BETAF*(logf(s0) + m0);
    out1[node] = BETAF*(logf(s1) + m1);
  }
}

// ---------- fused: logz + obs-lse + NLL + KL score; 16 lanes/node ----------
__launch_bounds__(256)
__global__ void k_final2(const int* __restrict__ row_s, const int* __restrict__ dst_csr,
                         const float* __restrict__ a0, const float* __restrict__ a1,
                         const float* __restrict__ r0, const float* __restrict__ r1,
                         const float* __restrict__ V0, const float* __restrict__ V1,
                         float* __restrict__ out, float* __restrict__ partial){
  int node = blockIdx.x*16 + (threadIdx.x >> 4);
  int t = threadIdx.x & 15;
  float nll = 0.f;
  if (node < NN){
    int j0 = row_s[node], j1 = row_s[node+1];
    if (j0 == j1){
      if (t == 0) out[1 + node] = 0.f;
    } else {
      float mq0=-INFINITY, sq0=0.f, mq1=-INFINITY, sq1=0.f;
      float ma0=-INFINITY, sa0=0.f, ma1=-INFINITY, sa1=0.f;
      for (int j = j0 + t; j < j1; j += 16){
        int d = dst_csr[j];
        float q0 = (r0[j] + V0[d]) * INVB;
        float q1 = (r1[j] + V1[d]) * INVB;
        float la0 = logf(a0[j] + 1e-12f);
        float la1 = logf(a1[j] + 1e-12f);
        float mn;
        mn = fmaxf(mq0, q0); sq0 = sc_(sq0, mq0, mn) + expf(q0 - mn); mq0 = mn;
        mn = fmaxf(mq1, q1); sq1 = sc_(sq1, mq1, mn) + expf(q1 - mn); mq1 = mn;
        mn = fmaxf(ma0, la0); sa0 = sc_(sa0, ma0, mn) + expf(la0 - mn); ma0 = mn;
        mn = fmaxf(ma1, la1); sa1 = sc_(sa1, ma1, mn) + expf(la1 - mn); ma1 = mn;
      }
      lse16(mq0, sq0); lse16(mq1, sq1); lse16(ma0, sa0); lse16(ma1, sa1);
      float L0 = logf(sq0) + mq0, L1 = logf(sq1) + mq1;
      float O0 = logf(sa0) + ma0, O1 = logf(sa1) + ma1;
      float sca = 0.f;
      for (int j = j0 + t; j < j1; j += 16){
        int d = dst_csr[j];
        float la0 = logf(a0[j] + 1e-12f);
        float lp0 = la0 - O0;
        float p0 = expf(lp0);
        float ls0 = (r0[j] + V0[d]) * INVB - L0;
        nll -= p0 * ls0;
        sca += p0 * (lp0 - ls0);
        float la1 = logf(a1[j] + 1e-12f);
        float lp1 = la1 - O1;
        float p1 = expf(lp1);
        float ls1 = (r1[j] + V1[d]) * INVB - L1;
        nll -= p1 * ls1;
        sca += p1 * (lp1 - ls1);
      }
      red16(sca);
      if (t == 0) out[1 + node] = sca;
    }
  }
  #pragma unroll
  for (int off = 1; off < 64; off <<= 1) nll += __shfl_xor(nll, off, 64);
  __shared__ float wsum[4];
  if ((threadIdx.x & 63) == 0) wsum[threadIdx.x >> 6] = nll;
  __syncthreads();
  if (threadIdx.x == 0) partial[blockIdx.x] = wsum[0]+wsum[1]+wsum[2]+wsum[3];
}

__launch_bounds__(256)
__global__ void k_nllred(const float* __restrict__ partial, int np, float* __restrict__ out){
  float s = 0.f;
  for (int i = threadIdx.x; i < np; i += 256) s += partial[i];
  #pragma unroll
  for (int off = 1; off < 64; off <<= 1) s += __shfl_xor(s, off, 64);
  __shared__ float wsum[4];
  if ((threadIdx.x & 63) == 0) wsum[threadIdx.x >> 6] = s;
  __syncthreads();
  if (threadIdx.x == 0) out[0] = (wsum[0]+wsum[1]+wsum[2]+wsum[3]) * (1.f/NN);
}

// =======================================================================
extern "C" void kernel_launch(void* const* d_in, const int* in_sizes, int n_in,
                              void* d_out, int out_size, void* d_ws, size_t ws_size,
                              hipStream_t stream){
  const float* x    = (const float*)d_in[0];
  const int*   ei   = (const int*)d_in[1];
  const float* W0   = (const float*)d_in[2];
  const float* as0  = (const float*)d_in[3];
  const float* ad0  = (const float*)d_in[4];
  const float* W1   = (const float*)d_in[5];
  const float* as1  = (const float*)d_in[6];
  const float* ad1  = (const float*)d_in[7];
  const float* Ws1  = (const float*)d_in[8];
  const float* bs1  = (const float*)d_in[9];
  const float* ws2  = (const float*)d_in[10];
  const float* bs2  = (const float*)d_in[11];
  const float* Wm1  = (const float*)d_in[12];
  const float* bm1  = (const float*)d_in[13];
  const float* wm2  = (const float*)d_in[14];
  const float* bm2  = (const float*)d_in[15];
  const float* lam1 = (const float*)d_in[16];
  float* out = (float*)d_out;

  char* p = (char*)d_ws;
  auto alloc = [&](size_t bytes)->void*{
    void* r = (void*)p;
    p += (bytes + 255) & ~(size_t)255;
    return r;
  };
  _Float16* Hh   = (_Float16*)alloc((size_t)NN*128*2);   // layer-1 projection (f16)
  _Float16* h1f  = (_Float16*)alloc((size_t)NN*128*2);
  _Float16* U01  = (_Float16*)alloc((size_t)NN*256*2);   // [u0 | u1] per node
  _Float16* V01  = (_Float16*)alloc((size_t)NN*256*2);   // [v0 | v1] per node
  _Float16* Wt   = (_Float16*)alloc((size_t)4*128*128*2);
  float* tab     = (float*)alloc((size_t)128*128*4);
  int*   src_of_j= (int*)alloc((size_t)NE*4);
  int*   dst_csr = (int*)alloc((size_t)NE*4);
  int*   src_dord= (int*)alloc((size_t)NE*4);
  int*   rs_dord = (int*)alloc((size_t)NE*4);
  int*   row_s   = (int*)alloc((size_t)(NN+1)*4);
  int*   row_d   = (int*)alloc((size_t)(NN+1)*4);
  int*   cur_s   = (int*)alloc((size_t)NN*4);
  int*   cur_d   = (int*)alloc((size_t)NN*4);
  int*   partA   = (int*)alloc(256*4);
  int*   partB   = (int*)alloc(256*4);
  unsigned char* d8o = (unsigned char*)alloc(NN);
  unsigned char* d8i = (unsigned char*)alloc(NN);
  float* alS     = (float*)alloc((size_t)NN*8*4);
  float* alD     = (float*)alloc((size_t)NN*8*4);
  float* acsr0   = (float*)alloc((size_t)NE*4);
  float* acsr1   = (float*)alloc((size_t)NE*4);
  float* rcsr0   = (float*)alloc((size_t)NE*4);
  float* rcsr1   = (float*)alloc((size_t)NE*4);
  float* V0a = (float*)alloc((size_t)NN*4);
  float* V0b = (float*)alloc((size_t)NN*4);
  float* V1a = (float*)alloc((size_t)NN*4);
  float* V1b = (float*)alloc((size_t)NN*4);
  float* nllpart = (float*)alloc((size_t)4*((NN+15)/16 + 1));

  _Float16* W0t = Wt;
  _Float16* W1t = Wt + 128*128;
  _Float16* Wut = Wt + 2*128*128;
  _Float16* Wvt = Wt + 3*128*128;

  const int G_E    = (NE + 255)/256;      // 3125
  const int G_gemm = (NN + 63)/64;        // 782
  const int G_n4   = (NN + 3)/4;          // 12500
  const int G_n16  = (NN + 15)/16;        // 3125
  const int G_e16  = (NE + 15)/16;        // 50000
  const int NPART  = (NN + 255)/256;      // 196

  // ---- CSR build ----
  hipMemsetAsync(cur_s, 0, (size_t)NN*4, stream);
  hipMemsetAsync(cur_d, 0, (size_t)NN*4, stream);
  k_hist<<<G_E, 256, 0, stream>>>(ei, cur_s, cur_d);
  k_scan_a<<<dim3(NPART,2), 256, 0, stream>>>(cur_s, cur_d, row_s, row_d, partA, partB, NN);
  k_scan_b<<<dim3(1,2), 256, 0, stream>>>(partA, partB, NPART);
  k_scan_c<<<dim3(NPART,2), 256, 0, stream>>>(row_s, row_d, cur_s, cur_d, partA, partB, NN);
  k_scatter<<<G_E, 256, 0, stream>>>(ei, cur_s, cur_d, src_of_j, dst_csr, src_dord, rs_dord);
  k_deg<<<(NN+255)/256, 256, 0, stream>>>(row_s, row_d, d8o, d8i);

  // ---- weight prep + structural table ----
  k_prepw<<<(4*128*128+255)/256, 256, 0, stream>>>(W0, W1, Wm1, Wt);
  k_strtab<<<(128*128+255)/256, 256, 0, stream>>>(Ws1, bs1, ws2, bs2, tab);

  // ---- layer 1: x @ {W0, Wu, Wv} + al epilogue ----
  k_gemm3<0,0><<<G_gemm, 256, 0, stream>>>(x, W0t, Wut, Wvt, bm1, as0, ad0,
                                           Hh, U01, V01, alS, alD, NN);
  k_att<true><<<G_n4, 256, 0, stream>>>(row_d, src_dord, rs_dord, alS, alD, Hh, acsr0, h1f);

  // ---- layer 2: h1 @ {W1, Wu, Wv} + al epilogue (no H store) ----
  k_gemm3<1,1><<<G_gemm, 256, 0, stream>>>(h1f, W1t, Wut, Wvt, bm1, as1, ad1,
                                           nullptr, U01, V01, alS, alD, NN);
  k_att<false><<<G_n4, 256, 0, stream>>>(row_d, src_dord, rs_dord, alS, alD, nullptr, acsr1, nullptr);

  // ---- per-edge rewards (src-CSR order) ----
  k_edge5<<<G_e16, 256, 0, stream>>>(src_of_j, dst_csr, d8o, d8i, tab,
                                     U01, V01, wm2, bm2, lam1, rcsr0, rcsr1);

  // ---- soft value iteration ----
  hipMemsetAsync(V0a, 0, (size_t)NN*4, stream);
  hipMemsetAsync(V1a, 0, (size_t)NN*4, stream);
  float* v0i = V0a; float* v0o = V0b;
  float* v1i = V1a; float* v1o = V1b;
  for (int it = 0; it < 5; ++it){
    k_svi<<<G_n16, 256, 0, stream>>>(row_s, dst_csr, rcsr0, rcsr1, v0i, v1i, v0o, v1o);
    float* t;
    t = v0i; v0i = v0o; v0o = t;
    t = v1i; v1i = v1o; v1o = t;
  }

  // ---- fused logz + obs-lse + loss + score ----
  k_final2<<<G_n16, 256, 0, stream>>>(row_s, dst_csr, acsr0, acsr1, rcsr0, rcsr1,
                                      v0i, v1i, out, nllpart);
  k_nllred<<<1, 256, 0, stream>>>(nllpart, G_n16, out);
}